// Round 4
// baseline (126.361 us; speedup 1.0000x reference)
//
#include <hip/hip_runtime.h>
#include <math.h>

#define B 8
#define T 128
#define NKEY 127   // t-1
#define KDIM 64    // Q_DIM == KV_DIM
#define NH 4       // heads
#define CH 256     // NH*KDIM output channels

typedef _Float16 half8 __attribute__((ext_vector_type(8)));  // 8 fp16 (4 VGPRs)
typedef __fp16 fp16x2 __attribute__((ext_vector_type(2)));   // cvt_pkrtz result type
typedef float floatx4 __attribute__((ext_vector_type(4)));   // MFMA C/D

// ---- async global->LDS, 16B per lane: LDS dest = uniform base + lane*16,
// global src is PER-LANE. No VGPR round-trip, no cvt in staging path. ----
typedef __attribute__((address_space(1))) const unsigned GBuf;
typedef __attribute__((address_space(3))) unsigned LBuf;
__device__ __forceinline__ void gload_lds16(const void* g, void* lds) {
    __builtin_amdgcn_global_load_lds((GBuf*)g, (LBuf*)lds, 16, 0, 0);
}

// 8x f32 -> 8x fp16 via v_cvt_pkrtz (4 instrs). RTZ is <=1 ulp (vs RNE 0.5);
// score-path absmax rises ~2x at most -- far under the 3.5e-3 threshold.
__device__ __forceinline__ half8 cvt8_rtz(const float4& a, const float4& b) {
    fp16x2 p0 = __builtin_amdgcn_cvt_pkrtz(a.x, a.y);
    fp16x2 p1 = __builtin_amdgcn_cvt_pkrtz(a.z, a.w);
    fp16x2 p2 = __builtin_amdgcn_cvt_pkrtz(b.x, b.y);
    fp16x2 p3 = __builtin_amdgcn_cvt_pkrtz(b.z, b.w);
    half8 h;
    h[0] = (_Float16)p0[0]; h[1] = (_Float16)p0[1];
    h[2] = (_Float16)p1[0]; h[3] = (_Float16)p1[1];
    h[4] = (_Float16)p2[0]; h[5] = (_Float16)p2[1];
    h[6] = (_Float16)p3[0]; h[7] = (_Float16)p3[1];
    return h;
}

// RNE for the A-side (Wk, loaded once in the prologue -- keep best rounding).
__device__ __forceinline__ half8 cvt8_rne(const float4& a, const float4& b) {
    half8 h;
    h[0] = (_Float16)a.x; h[1] = (_Float16)a.y;
    h[2] = (_Float16)a.z; h[3] = (_Float16)a.w;
    h[4] = (_Float16)b.x; h[5] = (_Float16)b.y;
    h[6] = (_Float16)b.z; h[7] = (_Float16)b.w;
    return h;
}

// R11: latency-phase surgery. R8/R9/R10 all land at 44-48us despite occupancy
// 32/41/60% -> NOT occupancy-bound; all pipes idle -> phase-lockstep latency:
// every block runs the same phase at once, and staging (global->VGPR->cvt->LDS,
// 4 loads in flight at VGPR=32) plus Phase B (64 scalar global loads, 200-900cy)
// serialize behind 5 barriers. Fixes:
//  (1) kv staged fp32 ROW-MAJOR via global_load_lds (4 instrs/wave, latency
//      parked in vmcnt while waves run the Wq/Wk prologue). cvt->fp16 moves
//      into the score loop as v_cvt_pkrtz.
//  (2) Phase B reads kv from LDS (b128, conflict-free: cols tile all banks),
//      probs via register __shfl -- zero global traffic, one barrier removed.
//  (3) Epilogue algebra: ws*tanh = ws - 2ws/(e^{2x}+1), sum(ws) hoisted.
// Barriers 5 -> 3. LDS 39936 B -> 4 blocks/CU (32 waves = 100% cap).
__global__ __launch_bounds__(512, 8)
void attn_kernel(const float* __restrict__ q_x,   // (B,T,64)
                 const float* __restrict__ kv_x,  // (B,T,127,64)
                 const float* __restrict__ Wk,    // (256,64)
                 const float* __restrict__ Wq,    // (256,64)
                 const float* __restrict__ Wv,    // (256,64)
                 const float* __restrict__ bias,  // (64,)
                 const float* __restrict__ Ws,    // (1,64)
                 const float* __restrict__ bs,    // (1,) -- cancels in softmax
                 float* __restrict__ out)         // (B,T,256)
{
    __shared__ __align__(16) float kv_lds[128][64];  // 32 KB fp32 kv, row-major
    __shared__ __align__(16) float qb_lds[CH];       // 1 KB query+bias
    __shared__ __align__(16) float pp_lds[8][128];   // 4 KB per-wave score partials
    __shared__ __align__(16) float wkv2[8][64];      // 2 KB per-wave wkv partials

    const int bt   = blockIdx.x;
    const int tid  = threadIdx.x;
    const int wid  = tid >> 6;    // 0..7
    const int lane = tid & 63;
    const int col  = lane & 15;   // MFMA n/m lane index
    const int quad = lane >> 4;   // MFMA k-group / row-group
    const int h    = wid & 3;     // head
    const int role = wid >> 2;    // j-half (scores) / n-half (Phase B)

    const float* __restrict__ kvg = kv_x + (size_t)bt * NKEY * KDIM;

    // ---- stage kv -> LDS rows, async. 32 x 1KB instrs (4/wave), row-major.
    // Pad row 127 re-reads row 126 (branchless, content masked by prob=0). ----
    {
        const char* gb = (const char*)kvg;
        #pragma unroll
        for (int w = 0; w < 4; ++w) {
            const int idx = wid * 4 + w;            // wave-uniform chunk 0..31
            int off = idx * 1024 + lane * 16;       // byte offset in kv block
            off = (off >= NKEY * 256) ? off - 256 : off;   // row127 -> row126
            gload_lds16(gb + off, &kv_lds[idx * 4][0]);
        }
    }

    // ---- A-fragments: this wave's 32 Wk rows (j-half of head h), fp16 RNE ----
    // lane holds Wk[h*64 + role*32 + jtl*16 + col][ks*32 + quad*8 + j]
    half8 ah[2][2];
    #pragma unroll
    for (int jtl = 0; jtl < 2; ++jtl)
        #pragma unroll
        for (int ks = 0; ks < 2; ++ks) {
            const float* wrow = Wk + (size_t)(h * 64 + role * 32 + jtl * 16 + col) * KDIM
                                   + ks * 32 + quad * 8;
            float4 a = *(const float4*)wrow;
            float4 b = *(const float4*)(wrow + 4);
            ah[jtl][ks] = cvt8_rne(a, b);
        }

    // ---- query_j + bias for all 256 channels (thread pairs split k) ----
    {
        const int c = tid >> 1, kh = tid & 1;
        const float4* Wq4 = (const float4*)(Wq + (size_t)c * KDIM + kh * 32);
        const float4* q4g = (const float4*)(q_x + (size_t)bt * KDIM + kh * 32);
        float4 qa = make_float4(0.f, 0.f, 0.f, 0.f);
        #pragma unroll
        for (int i = 0; i < 8; ++i) {
            float4 w = Wq4[i];
            float4 q4 = q4g[i];
            qa.x = fmaf(q4.x, w.x, qa.x);
            qa.y = fmaf(q4.y, w.y, qa.y);
            qa.z = fmaf(q4.z, w.z, qa.z);
            qa.w = fmaf(q4.w, w.w, qa.w);
        }
        float r = (qa.x + qa.y) + (qa.z + qa.w);
        r += __shfl_xor(r, 1, 64);
        if (kh == 0) qb_lds[c] = r + bias[c & 63];
    }

    __syncthreads();   // B1: kv staged (vmcnt drained), qb ready

    // ---- qb folded into MFMA C-init; folded ws per lane ----
    // C/D layout: col = lane&15 = n, row = quad*4 + r = j within jtl-tile.
    floatx4 qb4[2];
    float4  ws2[2];
    float   wssum = 0.f;
    #pragma unroll
    for (int jtl = 0; jtl < 2; ++jtl) {
        qb4[jtl] = *(const floatx4*)&qb_lds[h * 64 + role * 32 + jtl * 16 + quad * 4];
        float4 w = *(const float4*)&Ws[role * 32 + jtl * 16 + quad * 4];
        wssum += (w.x + w.y) + (w.z + w.w);
        ws2[jtl] = make_float4(-2.f * w.x, -2.f * w.y, -2.f * w.z, -2.f * w.w);
    }

    // ---- scores: 8 n-tiles; B-frags read fp32 from LDS rows + pkrtz cvt ----
    #pragma unroll
    for (int nt = 0; nt < 8; ++nt) {
        const float* krow = &kv_lds[nt * 16 + col][quad * 8];
        float4 f0 = *(const float4*)(krow);        // ks=0: k = quad*8 + 0..3
        float4 f1 = *(const float4*)(krow + 4);    //        k = quad*8 + 4..7
        float4 f2 = *(const float4*)(krow + 32);   // ks=1: k = 32+quad*8+0..3
        float4 f3 = *(const float4*)(krow + 36);
        half8 b0 = cvt8_rtz(f0, f1);
        half8 b1 = cvt8_rtz(f2, f3);

        float partial = wssum;   // sum_j ws_j * 1  (tanh -> 1 - 2r fold)
        #pragma unroll
        for (int jtl = 0; jtl < 2; ++jtl) {
            floatx4 c = qb4[jtl];   // acc init = query+bias (keys add onto it)
            c = __builtin_amdgcn_mfma_f32_16x16x32_f16(ah[jtl][0], b0, c, 0, 0, 0);
            c = __builtin_amdgcn_mfma_f32_16x16x32_f16(ah[jtl][1], b1, c, 0, 0, 0);
            #pragma unroll
            for (int r = 0; r < 4; ++r) {
                float e  = __expf(2.f * c[r]);
                float rc = __builtin_amdgcn_rcpf(e + 1.f);
                partial  = fmaf((&ws2[jtl].x)[r], rc, partial);
            }
        }
        partial += __shfl_xor(partial, 16, 64);   // reduce across quads (same col)
        partial += __shfl_xor(partial, 32, 64);
        if (lane < 16) pp_lds[wid][nt * 16 + lane] = partial;
    }

    __syncthreads();   // B2: all score partials written

    // ---- softmax over 127 real keys, fully register-resident after this ----
    float pa, pb, invl;
    {
        float s_a = pp_lds[h][lane]      + pp_lds[4 + h][lane];
        float s_b = pp_lds[h][64 + lane] + pp_lds[4 + h][64 + lane];
        if (lane == 63) s_b = -1e30f;          // mask pad key 127
        float mx = fmaxf(s_a, s_b);
        #pragma unroll
        for (int off = 32; off > 0; off >>= 1)
            mx = fmaxf(mx, __shfl_xor(mx, off, 64));
        pa = __expf(s_a - mx);
        pb = __expf(s_b - mx);                 // lane 63 -> 0
        float ls = pa + pb;
        #pragma unroll
        for (int off = 32; off > 0; off >>= 1)
            ls += __shfl_xor(ls, off, 64);
        invl = 1.f / ls;                       // all waves of head h hold invl
    }

    // ---- Phase B: wkv partial over this wave's 64-key half, all from LDS ----
    // lane reads kv[n0 + 4i + quad][(lane&15)*4 ..+3] (b128, conflict-free:
    // cols tile all 32 banks, rows alias 2-way=free). p[n] via register shfl.
    {
        const float ps = role ? pb : pa;       // p for n = role*64 + srclane
        const int   c4 = (lane & 15) * 4;
        floatx4 acc = {0.f, 0.f, 0.f, 0.f};
        #pragma unroll
        for (int i = 0; i < 16; ++i) {
            float p  = __shfl(ps, i * 4 + quad, 64);
            float4 v = *(const float4*)&kv_lds[role * 64 + i * 4 + quad][c4];
            acc[0] = fmaf(p, v.x, acc[0]);
            acc[1] = fmaf(p, v.y, acc[1]);
            acc[2] = fmaf(p, v.z, acc[2]);
            acc[3] = fmaf(p, v.w, acc[3]);
        }
        #pragma unroll
        for (int k = 0; k < 4; ++k) {
            acc[k] += __shfl_xor(acc[k], 16, 64);
            acc[k] += __shfl_xor(acc[k], 32, 64);
        }
        if (lane < 16) {
            float4 o = make_float4(acc[0] * invl, acc[1] * invl,
                                   acc[2] * invl, acc[3] * invl);
            *(float4*)&wkv2[wid][c4] = o;
        }
    }

    __syncthreads();   // B3: wkv partials visible cross-wave

    // ---- Phase C: out[c] = (wkv_half0 + wkv_half1) . Wv[c,:] (pair-split k) ----
    {
        const int c = tid >> 1, kh = tid & 1;
        const int hc = c >> 6;                 // head of channel c
        const float4* wa  = (const float4*)&wkv2[hc][kh * 32];
        const float4* wb  = (const float4*)&wkv2[4 + hc][kh * 32];
        const float4* Wv4 = (const float4*)(Wv + (size_t)c * KDIM + kh * 32);
        float4 oa = make_float4(0.f, 0.f, 0.f, 0.f);
        #pragma unroll
        for (int i = 0; i < 8; ++i) {
            float4 w = Wv4[i];
            float4 v = wa[i];                  // broadcast reads
            float4 u = wb[i];
            oa.x = fmaf(v.x + u.x, w.x, oa.x);
            oa.y = fmaf(v.y + u.y, w.y, oa.y);
            oa.z = fmaf(v.z + u.z, w.z, oa.z);
            oa.w = fmaf(v.w + u.w, w.w, oa.w);
        }
        float r = (oa.x + oa.y) + (oa.z + oa.w);
        r += __shfl_xor(r, 1, 64);
        if (kh == 0) out[(size_t)bt * CH + c] = r;
    }
}

extern "C" void kernel_launch(void* const* d_in, const int* in_sizes, int n_in,
                              void* d_out, int out_size, void* d_ws, size_t ws_size,
                              hipStream_t stream) {
    const float* q_x  = (const float*)d_in[0];
    const float* kv_x = (const float*)d_in[1];
    const float* Wk   = (const float*)d_in[2];
    const float* Wq   = (const float*)d_in[3];
    const float* Wv   = (const float*)d_in[4];
    const float* bias = (const float*)d_in[5];
    const float* Ws   = (const float*)d_in[6];
    const float* bs   = (const float*)d_in[7];
    float* out = (float*)d_out;

    attn_kernel<<<dim3(B * T), dim3(512), 0, stream>>>(
        q_x, kv_x, Wk, Wq, Wv, bias, Ws, bs, out);
}

// Round 8
// 116.496 us; speedup vs baseline: 1.0847x; 1.0847x over previous
//
#include <hip/hip_runtime.h>
#include <math.h>

#define B 8
#define T 128
#define NKEY 127   // t-1
#define NPAD 128   // padded key count (score row 127 forced to prob 0)
#define KDIM 64    // Q_DIM == KV_DIM
#define NH 4       // heads
#define CH 256     // NH*KDIM output channels

typedef _Float16 half8v __attribute__((ext_vector_type(8)));  // 8 fp16 (4 VGPRs)
typedef float floatx4 __attribute__((ext_vector_type(4)));    // MFMA C/D

// tanh(x) = 1 - 2/(e^{2x}+1). Saturates correctly at +/-inf, no clamp needed.
__device__ __forceinline__ float fast_tanh(float x) {
    float e = __expf(2.f * x);
    float r = __builtin_amdgcn_rcpf(e + 1.f);
    return fmaf(-2.f, r, 1.f);
}

// 8x float -> fp16 RNE (v_cvt_f16_f32). fp16 2^-11 half-ulp on both operands:
// numerically verified in R9/R10 (absmax 4.88e-4, same as bf16 hi/lo 2-pass).
__device__ __forceinline__ half8v cvt8_rne(const float4& a, const float4& b) {
    half8v h;
    h[0] = (_Float16)a.x; h[1] = (_Float16)a.y;
    h[2] = (_Float16)a.z; h[3] = (_Float16)a.w;
    h[4] = (_Float16)b.x; h[5] = (_Float16)b.y;
    h[6] = (_Float16)b.z; h[7] = (_Float16)b.w;
    return h;
}

// R15: strict A/B round after three correctness failures (R12/R13/R14).
// This is the R8 champion (44.2us dispatch, PASSED) byte-identical EXCEPT one
// substitution: the bf16 hi/lo 2-pass MFMA path becomes fp16 single-pass
// (R9/R10-verified numerics). Explicitly KEPT from R8: zero-init accumulator
// with qb added in the epilogue (NOT C-init), scalar qbv/wsv loads, in-loop
// quad reduction, softmax, Phase-B global column reads, Phase C. The R14
// suspects (deferred reduce, floatx4 qb/ws loads, C-init at 4 jt) are OUT.
__global__ __launch_bounds__(256, 2)
void attn_kernel(const float* __restrict__ q_x,   // (B,T,64)
                 const float* __restrict__ kv_x,  // (B,T,127,64)
                 const float* __restrict__ Wk,    // (256,64)
                 const float* __restrict__ Wq,    // (256,64)
                 const float* __restrict__ Wv,    // (256,64)
                 const float* __restrict__ bias,  // (64,)
                 const float* __restrict__ Ws,    // (1,64)
                 const float* __restrict__ bs,    // (1,) -- cancels in softmax
                 float* __restrict__ out)         // (B,T,256)
{
    __shared__ __align__(16) _Float16 frag[16][64][8];   // 16 KB: fp16 B-frags
    __shared__ float qb_lds[CH];                         // 1 KB: query+bias per channel
    __shared__ float p_lds[NH][NPAD];                    // 2 KB: scores then probs
    __shared__ __align__(16) float wkv_lds[NH][KDIM];    // 1 KB -> total 20480 B

    const int bt   = blockIdx.x;
    const int tid  = threadIdx.x;
    const int h    = tid >> 6;    // wave index == head index
    const int lane = tid & 63;
    const int col  = lane & 15;   // MFMA n/m lane index
    const int quad = lane >> 4;   // MFMA k-group / row-group

    const float* __restrict__ kvg = kv_x + (size_t)bt * NKEY * KDIM;

    // ---- convert kv (global) -> fragment-ordered fp16 LDS ----
    // chunk = nt*2+ks; write addr = chunk*1024 + lane*16: lane-linear, 0 conflicts.
    // Fragment content: kv[nt*16 + (lane&15)][ks*32 + (lane>>4)*8 + j]
    #pragma unroll
    for (int w = 0; w < 4; ++w) {
        const int chunk = w * 4 + h;          // each wave does 4 chunks
        const int nt = chunk >> 1, ks = chunk & 1;
        const int n  = nt * 16 + (lane & 15);
        const int k0 = ks * 32 + (lane >> 4) * 8;
        float4 a = make_float4(0.f, 0.f, 0.f, 0.f);
        float4 b = make_float4(0.f, 0.f, 0.f, 0.f);
        if (n < NKEY) {
            const float* p = kvg + (size_t)n * KDIM + k0;
            a = *(const float4*)p;
            b = *(const float4*)(p + 4);
        }
        *(half8v*)&frag[chunk][lane][0] = cvt8_rne(a, b);
    }

    // ---- query_j + bias -> qb_lds[channel] ----
    {
        const float4* Wq4 = (const float4*)(Wq + (size_t)tid * KDIM);
        const float4* q4g = (const float4*)(q_x + (size_t)bt * KDIM);
        float4 qa = {0.f, 0.f, 0.f, 0.f};
        #pragma unroll
        for (int i = 0; i < 16; ++i) {
            float4 w = Wq4[i];
            float4 q4 = q4g[i];
            qa.x = fmaf(q4.x, w.x, qa.x);
            qa.y = fmaf(q4.y, w.y, qa.y);
            qa.z = fmaf(q4.z, w.z, qa.z);
            qa.w = fmaf(q4.w, w.w, qa.w);
        }
        qb_lds[tid] = (qa.x + qa.y) + (qa.z + qa.w) + bias[tid & 63];
    }

    // ---- A-fragments: Wk rows of this head, fp16 RNE ----
    // A layout: lane holds Wk[h*64 + jt*16 + col][ks*32 + quad*8 + j]
    half8v ah[4][2];
    #pragma unroll
    for (int jt = 0; jt < 4; ++jt)
        #pragma unroll
        for (int ks = 0; ks < 2; ++ks) {
            const float* wrow = Wk + (size_t)(h * 64 + jt * 16 + col) * KDIM
                                   + ks * 32 + quad * 8;
            float4 a = *(const float4*)wrow;
            float4 b = *(const float4*)(wrow + 4);
            ah[jt][ks] = cvt8_rne(a, b);
        }

    __syncthreads();   // barrier: frags + qb ready

    // ---- per-lane qb / ws for epilogue: j = jt*16 + quad*4 + r ----
    float qbv[4][4], wsv[4][4];
    #pragma unroll
    for (int jt = 0; jt < 4; ++jt)
        #pragma unroll
        for (int r = 0; r < 4; ++r) {
            int j = jt * 16 + quad * 4 + r;
            qbv[jt][r] = qb_lds[h * 64 + j];
            wsv[jt][r] = Ws[j];
        }

    // ---- scores: 8 n-tiles of 16 keys; single-pass fp16 MFMA ----
    #pragma unroll
    for (int nt = 0; nt < 8; ++nt) {
        half8v b0 = *(const half8v*)&frag[nt * 2 + 0][lane][0];
        half8v b1 = *(const half8v*)&frag[nt * 2 + 1][lane][0];

        floatx4 acc[4];
        #pragma unroll
        for (int jt = 0; jt < 4; ++jt) {
            floatx4 c = {0.f, 0.f, 0.f, 0.f};
            c = __builtin_amdgcn_mfma_f32_16x16x32_f16(ah[jt][0], b0, c, 0, 0, 0);
            c = __builtin_amdgcn_mfma_f32_16x16x32_f16(ah[jt][1], b1, c, 0, 0, 0);
            acc[jt] = c;
        }

        // epilogue: score[n] = sum_j tanh(key + qb[j]) * ws[j]
        // D layout: col = lane&15 = n in tile, row = quad*4 + r = j in jt
        float partial = 0.f;
        #pragma unroll
        for (int jt = 0; jt < 4; ++jt)
            #pragma unroll
            for (int r = 0; r < 4; ++r)
                partial = fmaf(fast_tanh(acc[jt][r] + qbv[jt][r]), wsv[jt][r], partial);
        partial += __shfl_xor(partial, 16, 64);   // reduce across quads (same col)
        partial += __shfl_xor(partial, 32, 64);
        if (lane < 16) p_lds[h][nt * 16 + lane] = partial;
    }
    // no barrier: wave h is sole writer+reader of p_lds[h][*] (DS in-order)

    // ---- softmax over the 127 real keys (2 scores per lane) ----
    float invl;
    {
        float s_a = p_lds[h][lane];
        float s_b = p_lds[h][64 + lane];
        if (lane == 63) s_b = -1e30f;          // mask pad row 127
        float mx = fmaxf(s_a, s_b);
        #pragma unroll
        for (int off = 32; off > 0; off >>= 1)
            mx = fmaxf(mx, __shfl_xor(mx, off, 64));
        float pa = __expf(s_a - mx);
        float pb = __expf(s_b - mx);           // lane 63 -> 0
        float ls = pa + pb;
        #pragma unroll
        for (int off = 32; off > 0; off >>= 1)
            ls += __shfl_xor(ls, off, 64);
        invl = 1.f / ls;
        p_lds[h][lane]      = pa;              // unnormalized probs
        p_lds[h][64 + lane] = pb;              // p_lds[h][127] = 0 masks pad
    }

    // ---- Phase B: wkv[h][lane] = (sum_n p[n] * kv[n][lane]) / l ----
    // kv column reads from global: consecutive lanes -> consecutive addrs,
    // L2-hot (read during conversion ~us earlier). Probs broadcast from LDS.
    {
        const float* kvl = kvg + lane;
        float w0 = 0.f, w1 = 0.f, w2 = 0.f, w3 = 0.f;
        #pragma unroll 8
        for (int n4 = 0; n4 < NPAD; n4 += 4) {
            float4 p4 = *(const float4*)&p_lds[h][n4];       // uniform broadcast
            const int n3 = (n4 + 3 < NKEY) ? (n4 + 3) : 0;   // p4.w==0 there
            w0 = fmaf(p4.x, kvl[(size_t)(n4 + 0) * KDIM], w0);
            w1 = fmaf(p4.y, kvl[(size_t)(n4 + 1) * KDIM], w1);
            w2 = fmaf(p4.z, kvl[(size_t)(n4 + 2) * KDIM], w2);
            w3 = fmaf(p4.w, kvl[(size_t)n3 * KDIM], w3);
        }
        wkv_lds[h][lane] = ((w0 + w1) + (w2 + w3)) * invl;
    }
    // no barrier: wkv_lds[h] written and read only by wave h (DS in-order)

    // ---- Phase C: out[j] = wkv[h,:] . Wv[j,:] ----
    {
        const float4* Wv4 = (const float4*)(Wv + (size_t)tid * KDIM);
        const float4* wv_row = (const float4*)wkv_lds[h];
        float4 oa = {0.f, 0.f, 0.f, 0.f};
        #pragma unroll
        for (int i = 0; i < 16; ++i) {
            float4 w = Wv4[i];
            float4 c = wv_row[i];                        // broadcast
            oa.x = fmaf(c.x, w.x, oa.x);
            oa.y = fmaf(c.y, w.y, oa.y);
            oa.z = fmaf(c.z, w.z, oa.z);
            oa.w = fmaf(c.w, w.w, oa.w);
        }
        out[(size_t)bt * CH + tid] = (oa.x + oa.y) + (oa.z + oa.w);
    }
}

extern "C" void kernel_launch(void* const* d_in, const int* in_sizes, int n_in,
                              void* d_out, int out_size, void* d_ws, size_t ws_size,
                              hipStream_t stream) {
    const float* q_x  = (const float*)d_in[0];
    const float* kv_x = (const float*)d_in[1];
    const float* Wk   = (const float*)d_in[2];
    const float* Wq   = (const float*)d_in[3];
    const float* Wv   = (const float*)d_in[4];
    const float* bias = (const float*)d_in[5];
    const float* Ws   = (const float*)d_in[6];
    const float* bs   = (const float*)d_in[7];
    float* out = (float*)d_out;

    attn_kernel<<<dim3(B * T), dim3(256), 0, stream>>>(
        q_x, kv_x, Wk, Wq, Wv, bias, Ws, bs, out);
}